// Round 1
// 153.185 us; speedup vs baseline: 1.0273x; 1.0273x over previous
//
#include <hip/hip_runtime.h>
#include <math.h>

// B=8, C=128, N=4096, d=16, groups=32
// R17 = R16 gnprep+qkv VERBATIM + attn rewritten barrier-free.
//   R16 counters: attn 71us, MfmaUtil 22%, VALUBusy 33%, HBM 5.4%, Occ 17.9%,
//   LDS_BANK_CONFLICT 4.3M. Neither pipe busy -> per-tile __syncthreads for the
//   V double-buffer serializes the long chain (load->QK->exp->pack->shfl->PV->
//   stage->barrier) with only 2 waves/SIMD of TLP.
//   Fix: V is L2-resident (1MB/batch, XCD-pinned) and staging already streamed
//   it once per tile per block; read MFMA A-frags DIRECT from global (coalesced
//   2KB/wave per frag in the VT tiled layout), register-prefetch next tile's
//   kf + 8 V frags, delete ds_write/ds_read/barrier from the main loop.
//   Cost: 2x V L2 traffic (2MB/block -> ~131MB/XCD, floor ~32us) -- acceptable.
//   LDS now epilogue-overlay only (36.9KB). Predict attn 71->~45us, conflicts
//   ~0, MfmaUtil ~35, VALUBusy ~50.

typedef short v8s __attribute__((ext_vector_type(8)));   // 8 bf16 = 4 VGPRs
typedef float v16f __attribute__((ext_vector_type(16))); // 32x32 acc

__device__ __forceinline__ unsigned short f2bf_rne(float f) {
  unsigned u = __float_as_uint(f);
  u += 0x7fffu + ((u >> 16) & 1u);
  return (unsigned short)(u >> 16);
}

__device__ __forceinline__ v8s mk8(unsigned a, unsigned b, unsigned c, unsigned d) {
  union { unsigned u[4]; v8s s; } x;
  x.u[0] = a; x.u[1] = b; x.u[2] = c; x.u[3] = d;
  return x.s;
}

// pack two fp32 -> dword of 2 bf16 (truncation) in ONE v_perm_b32
__device__ __forceinline__ unsigned pack_trunc(float hi, float lo) {
  return __builtin_amdgcn_perm(__float_as_uint(hi), __float_as_uint(lo), 0x07060302u);
}

// tiled V element index: [b][j>>4][c][j&15]
#define VT(b, n, c) (((((size_t)(b) * 256 + ((n) >> 4)) << 7) + (c)) * 16 + ((n) & 15))

// ws byte offsets
#define WSB_MURS   0u
#define WSB_WCATB  4096u       // 160*128 bf16 = 40960
#define WSB_BCAT   49152u      // 160 f32
#define WSB_PWB    65536u      // 128*128 bf16 = 32768
#define WSB_QBF    131072u     // Q^T [B,16,N] bf16 = 1 MB
#define WSB_KBF    1310720u    // K [B,N,16] bf16 = 1 MB
#define WSB_VBF    2621440u    // 8 MB (tiled)

// ---------------------------------------------------------------------------
// gn_stats + prep fused. Grid 256 x 512 thr.  (VERBATIM from R16)
// ---------------------------------------------------------------------------
__global__ __launch_bounds__(512)
void gnprep_kernel(const float* __restrict__ x, float* __restrict__ mu_rs,
                   const float* __restrict__ qw, const float* __restrict__ qb,
                   const float* __restrict__ kw, const float* __restrict__ kb,
                   const float* __restrict__ vw, const float* __restrict__ vb,
                   const float* __restrict__ pw,
                   unsigned short* __restrict__ wcatb, float* __restrict__ bcat,
                   unsigned short* __restrict__ pwb) {
  const int id = blockIdx.x;
  {
    const float qs = 0.36067376022224085f;  // 0.25 * log2(e)
    int idx = id * 512 + threadIdx.x;
    if (idx < 160 * 128) {
      int o = idx >> 7, c = idx & 127;
      float val;
      if (o < 16)       val = qw[o * 128 + c] * qs;
      else if (o < 32)  val = kw[(o - 16) * 128 + c];
      else              val = vw[(o - 32) * 128 + c];
      wcatb[idx] = f2bf_rne(val);
    } else if (idx < 160 * 128 + 160) {
      int o = idx - 160 * 128;
      bcat[o] = (o < 16) ? qb[o] * qs : (o < 32) ? kb[o - 16] : vb[o - 32];
    } else if (idx < 160 * 128 + 160 + 128 * 128) {
      int j = idx - (160 * 128 + 160);
      pwb[j] = f2bf_rne(pw[j]);
    }
  }
  const int bg = (id & 7) * 32 + (id >> 3);   // XCD swizzle: batch = id & 7
  const float4* xp = (const float4*)(x + (size_t)bg * 16384);
  float s = 0.f, ss = 0.f;
#pragma unroll
  for (int u = 0; u < 8; ++u) {
    int i = threadIdx.x + u * 512;
    float4 v = xp[i];
    s  += v.x + v.y + v.z + v.w;
    ss += v.x * v.x + v.y * v.y + v.z * v.z + v.w * v.w;
  }
  for (int off = 32; off > 0; off >>= 1) {
    s  += __shfl_down(s, off, 64);
    ss += __shfl_down(ss, off, 64);
  }
  __shared__ float red[16];
  int lane = threadIdx.x & 63, wid = threadIdx.x >> 6;
  if (lane == 0) { red[wid * 2] = s; red[wid * 2 + 1] = ss; }
  __syncthreads();
  if (threadIdx.x == 0) {
    float S = 0.f, SS = 0.f;
    for (int w = 0; w < 8; ++w) { S += red[w * 2]; SS += red[w * 2 + 1]; }
    float mu  = S * (1.0f / 16384.0f);
    float var = SS * (1.0f / 16384.0f) - mu * mu;
    float rs  = rsqrtf(var + 1e-5f);
    mu_rs[bg * 2]     = mu;
    mu_rs[bg * 2 + 1] = rs;
  }
}

// ---------------------------------------------------------------------------
// R16 QKV: LDS-staged GEMM.  (VERBATIM from R16)
// ---------------------------------------------------------------------------
#define HS 136   // shorts per hs row (128 data + 8 pad); 16B-aligned rows

__global__ __launch_bounds__(512)
void qkv_kernel(const float* __restrict__ x, const float* __restrict__ gnw,
                const float* __restrict__ gnb, const float* __restrict__ mu_rs,
                const unsigned short* __restrict__ wcatb, const float* __restrict__ bcat,
                unsigned short* __restrict__ qTb, unsigned short* __restrict__ kbf,
                unsigned short* __restrict__ vbf) {
  __shared__ alignas(16) unsigned short hs[64 * HS];   // 17408 B
  __shared__ float scsh[128], shsh[128], bsh[160];
  const int id = blockIdx.x;
  const int b = id & 7, nb = (id >> 3) << 6;   // XCD-pinned batch
  const int t = threadIdx.x;
  const int w = t >> 6, lane = t & 63, h = lane >> 5, l = lane & 31;
  const int nsub = w & 1, og = w >> 1;

  if (t < 128) {
    float mu = mu_rs[(b * 32 + (t >> 2)) * 2];
    float rs = mu_rs[(b * 32 + (t >> 2)) * 2 + 1];
    float gw = gnw[t], gb = gnb[t];
    scsh[t] = rs * gw; shsh[t] = gb - mu * rs * gw;
  }
  if (t < 160) bsh[t] = bcat[t];
  __syncthreads();

  // ---- stage: thread = (sn = t&63, c-quad base c00 = (t>>6)*4), 4 iters ----
  const int sn = t & 63;
  const int c00 = (t >> 6) * 4;
  const float* xb = x + ((size_t)b * 128 << 12) + nb + sn;
#pragma unroll
  for (int it = 0; it < 4; ++it) {
    const int c0 = c00 + it * 32;    // wave-uniform
    float f0 = xb[(size_t)(c0)     << 12] * scsh[c0]     + shsh[c0];
    float f1 = xb[(size_t)(c0 + 1) << 12] * scsh[c0 + 1] + shsh[c0 + 1];
    float f2 = xb[(size_t)(c0 + 2) << 12] * scsh[c0 + 2] + shsh[c0 + 2];
    float f3 = xb[(size_t)(c0 + 3) << 12] * scsh[c0 + 3] + shsh[c0 + 3];
    uint2 u;
    u.x = (unsigned)f2bf_rne(f0) | ((unsigned)f2bf_rne(f1) << 16);
    u.y = (unsigned)f2bf_rne(f2) | ((unsigned)f2bf_rne(f3) << 16);
    *(uint2*)(&hs[sn * HS + c0]) = u;
  }
  __syncthreads();

  // ---- MFMA: wave (nsub, og); og0 -> ot{0,1}, og1..3 -> ot{2..4} ----
  const int n = nb + nsub * 32 + l;
  const int otbase = (og == 0) ? 0 : og + 1;
  v16f acc[2];
#pragma unroll
  for (int a2 = 0; a2 < 2; ++a2)
#pragma unroll
    for (int r = 0; r < 16; ++r) acc[a2][r] = 0.f;

#pragma unroll
  for (int ks = 0; ks < 8; ++ks) {
    v8s bf = *(const v8s*)(&hs[(nsub * 32 + l) * HS + ks * 16 + 8 * h]);
    {
      v8s af = *(const v8s*)(wcatb + (otbase * 32 + l) * 128 + ks * 16 + 8 * h);
      acc[0] = __builtin_amdgcn_mfma_f32_32x32x16_bf16(af, bf, acc[0], 0, 0, 0);
    }
    if (og == 0) {
      v8s af = *(const v8s*)(wcatb + (32 + l) * 128 + ks * 16 + 8 * h);
      acc[1] = __builtin_amdgcn_mfma_f32_32x32x16_bf16(af, bf, acc[1], 0, 0, 0);
    }
  }

  // ---- epilogue (unchanged) ----
  if (og == 0) {
    const size_t nqk = ((size_t)b * 4096 + n) << 4;
#pragma unroll
    for (int r = 0; r < 16; ++r) {
      int o = 4 * h + (r & 3) + 8 * (r >> 2);
      unsigned short bv = f2bf_rne(acc[0][r] + bsh[o]);
      if (o < 16) qTb[((size_t)(b * 16 + o) << 12) + n] = bv;
      else        kbf[nqk + o - 16] = bv;
    }
#pragma unroll
    for (int r = 0; r < 16; ++r) {
      int o = 32 + 4 * h + (r & 3) + 8 * (r >> 2);
      vbf[VT(b, n, o - 32)] = f2bf_rne(acc[1][r] + bsh[o]);
    }
  } else {
#pragma unroll
    for (int r = 0; r < 16; ++r) {
      int o = otbase * 32 + 4 * h + (r & 3) + 8 * (r >> 2);
      vbf[VT(b, n, o - 32)] = f2bf_rne(acc[0][r] + bsh[o]);
    }
  }
}

// ---------------------------------------------------------------------------
// R17 flash attention + fused proj: barrier-free main loop, V direct from L2.
// Grid 512 x 256 thr (4 waves: jsub = w&1, ihalf = w>>1).
// ---------------------------------------------------------------------------
#define OTS 136                   // O^T row stride in shorts (68 dwords)

__global__ __launch_bounds__(256)
void attn_kernel(const unsigned short* __restrict__ qTb,
                 const unsigned short* __restrict__ kbf,
                 const unsigned short* __restrict__ vbf,
                 const unsigned short* __restrict__ pwb,
                 const float* __restrict__ pb,
                 const float* __restrict__ x,
                 float* __restrict__ out) {
  // epilogue-only LDS: f32 combine overlay (36864 B) reused as O^T bf16
  __shared__ alignas(16) float ovs[9216];
  __shared__ float l_lds[64];
  __shared__ float pbs[128];

  const int id = blockIdx.x;
  const int b = id & 7, i0 = (id >> 3) << 6;   // XCD-pinned batch, 64-i tile
  const int t = threadIdx.x;
  const int w = t >> 6, lane = t & 63, h = lane >> 5, l = lane & 31;
  const int jsub = w & 1, ihalf = w >> 1;

  // per-lane base pointers (fragment-coalesced: lane(h,l) at byte l*32+h*16)
  const unsigned short* kg = kbf + ((size_t)b << 16) + jsub * 512 + l * 16 + 8 * h;
  const unsigned short* vg = vbf + ((size_t)b << 19) + jsub * 4096 + l * 16 + 8 * h;

  if (t < 128) pbs[t] = pb[t];
  if (t < 64) l_lds[t] = 0.f;

  // Q B-frag from Q^T [B,16,N]: 8 coalesced b16 loads, once per kernel
  const int iglob = i0 + ihalf * 32 + l;
  unsigned qd[4];
#pragma unroll
  for (int e = 0; e < 4; ++e) {
    unsigned lo = qTb[((size_t)(b * 16 + 8 * h + 2 * e) << 12) + iglob];
    unsigned hi = qTb[((size_t)(b * 16 + 8 * h + 2 * e + 1) << 12) + iglob];
    qd[e] = lo | (hi << 16);
  }
  const v8s qf = mk8(qd[0], qd[1], qd[2], qd[3]);

  v16f zc;
#pragma unroll
  for (int r = 0; r < 16; ++r) zc[r] = 0.f;
  v16f acc[4];
#pragma unroll
  for (int ct = 0; ct < 4; ++ct)
#pragma unroll
    for (int r = 0; r < 16; ++r) acc[ct][r] = 0.f;
  float ls = 0.f;

  __syncthreads();   // l_lds zeros visible before any epilogue atomicAdd

  // prologue: tile-0 K frag + 8 V frags into regs
  v8s kf = *(const v8s*)kg;
  v8s vf[8];
#pragma unroll
  for (int ct = 0; ct < 4; ++ct) {
    vf[2 * ct]     = *(const v8s*)(vg + ct * 512);
    vf[2 * ct + 1] = *(const v8s*)(vg + 2048 + ct * 512);
  }

#pragma unroll 2
  for (int tile = 0; tile < 64; ++tile) {
    const int tn = (tile + 1) & 63;   // wrap: harmless reload on last iter

    // issue next-tile loads FIRST; latency hidden under QK + softmax + PV
    v8s kn = *(const v8s*)(kg + (size_t)tn * 1024);
    v8s vn[8];
    const unsigned short* vt = vg + (size_t)tn * 8192;
#pragma unroll
    for (int ct = 0; ct < 4; ++ct) {
      vn[2 * ct]     = *(const v8s*)(vt + ct * 512);
      vn[2 * ct + 1] = *(const v8s*)(vt + 2048 + ct * 512);
    }

    // QK: S^T patch (rows j, cols i) -> P in regs
    v16f st = __builtin_amdgcn_mfma_f32_32x32x16_bf16(kf, qf, zc, 0, 0, 0);
    float pe[16];
#pragma unroll
    for (int r = 0; r < 16; ++r) { pe[r] = __builtin_amdgcn_exp2f(st[r]); ls += pe[r]; }
    unsigned G[8];
#pragma unroll
    for (int g = 0; g < 4; ++g) {
      G[2 * g]     = pack_trunc(pe[4 * g + 1], pe[4 * g]);
      G[2 * g + 1] = pack_trunc(pe[4 * g + 3], pe[4 * g + 2]);
    }
    // half-wave exchange (proven mapping): 4 shfl + selects
    unsigned S0 = h ? G[0] : G[2], S1 = h ? G[1] : G[3];
    unsigned S2 = h ? G[4] : G[6], S3 = h ? G[5] : G[7];
    unsigned R0 = (unsigned)__shfl_xor((int)S0, 32, 64);
    unsigned R1 = (unsigned)__shfl_xor((int)S1, 32, 64);
    unsigned R2 = (unsigned)__shfl_xor((int)S2, 32, 64);
    unsigned R3 = (unsigned)__shfl_xor((int)S3, 32, 64);
    v8s pf0 = h ? mk8(R0, R1, G[2], G[3]) : mk8(G[0], G[1], R0, R1);
    v8s pf1 = h ? mk8(R2, R3, G[6], G[7]) : mk8(G[4], G[5], R2, R3);

    // PV on current-tile register fragments (no LDS, no barrier)
#pragma unroll
    for (int ct = 0; ct < 4; ++ct) {
      acc[ct] = __builtin_amdgcn_mfma_f32_32x32x16_bf16(vf[2 * ct],     pf0, acc[ct], 0, 0, 0);
      acc[ct] = __builtin_amdgcn_mfma_f32_32x32x16_bf16(vf[2 * ct + 1], pf1, acc[ct], 0, 0, 0);
    }

    // rotate prefetch (copies vanish under unroll-2 renaming)
    kf = kn;
#pragma unroll
    for (int u = 0; u < 8; ++u) vf[u] = vn[u];
  }

  // ---- epilogue: jsub combine, then fused proj (logic identical to R16) ----
  atomicAdd(&l_lds[ihalf * 32 + l], ls);
  __syncthreads();   // l complete; ovs free

  float* const ov = ovs;   // f32 combine overlay
  if (jsub == 1) {
#pragma unroll
    for (int ct = 0; ct < 4; ++ct)
#pragma unroll
      for (int q = 0; q < 4; ++q) {
        float4 v4 = {acc[ct][4 * q], acc[ct][4 * q + 1],
                     acc[ct][4 * q + 2], acc[ct][4 * q + 3]};
        *(float4*)&ov[((ct * 2 + ihalf) * 32 + l) * 36 + 4 * h + 8 * q] = v4;
      }
  }
  __syncthreads();
  if (jsub == 0) {
#pragma unroll
    for (int ct = 0; ct < 4; ++ct)
#pragma unroll
      for (int q = 0; q < 4; ++q) {
        float4 v4 = *(float4*)&ov[((ct * 2 + ihalf) * 32 + l) * 36 + 4 * h + 8 * q];
        acc[ct][4 * q]     += v4.x;
        acc[ct][4 * q + 1] += v4.y;
        acc[ct][4 * q + 2] += v4.z;
        acc[ct][4 * q + 3] += v4.w;
      }
  }
  __syncthreads();   // ov reads complete; overlay reusable

  // jsub=0 waves write normalized O^T bf16 [n_local][c], stride OTS
  unsigned short* const oT = (unsigned short*)ovs;
  if (jsub == 0) {
    const float li = 1.f / l_lds[ihalf * 32 + l];
    const int nrow = ihalf * 32 + l;
#pragma unroll
    for (int ct = 0; ct < 4; ++ct)
#pragma unroll
      for (int r = 0; r < 16; r += 2) {
        int c = ct * 32 + 4 * h + (r & 3) + 8 * (r >> 2);   // even
        unsigned dw = (unsigned)f2bf_rne(acc[ct][r] * li) |
                      ((unsigned)f2bf_rne(acc[ct][r + 1] * li) << 16);
        *(unsigned*)(&oT[nrow * OTS + c]) = dw;
      }
  }
  __syncthreads();

  // fused proj: wave w -> e-tile w (32 e), both n-subs. out = pw@O + pb + x.
#pragma unroll
  for (int nsub = 0; nsub < 2; ++nsub) {
    v16f a2;
#pragma unroll
    for (int r = 0; r < 16; ++r) a2[r] = 0.f;
#pragma unroll
    for (int ks = 0; ks < 8; ++ks) {
      v8s bf = *(const v8s*)(&oT[(nsub * 32 + l) * OTS + ks * 16 + 8 * h]);
      v8s af = *(const v8s*)(pwb + (w * 32 + l) * 128 + ks * 16 + 8 * h);
      a2 = __builtin_amdgcn_mfma_f32_32x32x16_bf16(af, bf, a2, 0, 0, 0);
    }
    const int n = i0 + nsub * 32 + l;
#pragma unroll
    for (int r = 0; r < 16; ++r) {
      int e = w * 32 + 4 * h + (r & 3) + 8 * (r >> 2);
      size_t idx = ((size_t)(b * 128 + e) << 12) + n;
      out[idx] = a2[r] + pbs[e] + x[idx];
    }
  }
}

// ---------------------------------------------------------------------------
extern "C" void kernel_launch(void* const* d_in, const int* in_sizes, int n_in,
                              void* d_out, int out_size, void* d_ws, size_t ws_size,
                              hipStream_t stream) {
  const float* x   = (const float*)d_in[0];
  const float* gnw = (const float*)d_in[1];
  const float* gnb = (const float*)d_in[2];
  const float* qw  = (const float*)d_in[3];
  const float* qb  = (const float*)d_in[4];
  const float* kw  = (const float*)d_in[5];
  const float* kb  = (const float*)d_in[6];
  const float* vw  = (const float*)d_in[7];
  const float* vb  = (const float*)d_in[8];
  const float* pw  = (const float*)d_in[9];
  const float* pb  = (const float*)d_in[10];
  float* out = (float*)d_out;
  char* ws = (char*)d_ws;

  float* mu_rs = (float*)(ws + WSB_MURS);
  unsigned short* wcatb = (unsigned short*)(ws + WSB_WCATB);
  float* bcat = (float*)(ws + WSB_BCAT);
  unsigned short* pwb = (unsigned short*)(ws + WSB_PWB);
  unsigned short* qTb = (unsigned short*)(ws + WSB_QBF);
  unsigned short* kbf = (unsigned short*)(ws + WSB_KBF);
  unsigned short* vbf = (unsigned short*)(ws + WSB_VBF);

  hipLaunchKernelGGL(gnprep_kernel, dim3(256), dim3(512), 0, stream,
                     x, mu_rs, qw, qb, kw, kb, vw, vb, pw, wcatb, bcat, pwb);
  hipLaunchKernelGGL(qkv_kernel, dim3(512), dim3(512), 0, stream,
                     x, gnw, gnb, mu_rs, wcatb, bcat, qTb, kbf, vbf);
  hipLaunchKernelGGL(attn_kernel, dim3(512), dim3(256), 0, stream,
                     qTb, kbf, vbf, pwb, pb, x, out);
}